// Round 1
// baseline (3199.739 us; speedup 1.0000x reference)
//
#include <hip/hip_runtime.h>
#include <hip/hip_bf16.h>

// Performer (FAVOR+) non-causal linear attention, fp32 baseline.
// b=8,h=16 -> BH=128 heads; n=4096, d=64, m=256.

#define BH 128
#define NN 4096
#define DD 64
#define MM 256

__device__ __forceinline__ unsigned fkey(float f) {
    unsigned b = __float_as_uint(f);
    return (b & 0x80000000u) ? ~b : (b | 0x80000000u);
}
__device__ __forceinline__ float funkey(unsigned k) {
    unsigned b = (k & 0x80000000u) ? (k ^ 0x80000000u) : ~k;
    return __uint_as_float(b);
}

__constant__ float NORMALIZER_C = 0.35355339059327373f; // 64^-0.25
#define NORMALIZER 0.35355339059327373f
#define RATIO 0.0625f
#define EPSV 1e-4f

// ---------------- K1: per-head max of k_dash, plus diag_k ----------------
// grid = BH*16 blocks, 256 threads. thread t <-> m=t. 256 rows per block.
__global__ __launch_bounds__(256, 2) void k1_maxdiag(
        const float* __restrict__ kmat, const float* __restrict__ proj,
        unsigned* __restrict__ mkKey, float* __restrict__ diagK) {
    const int head = blockIdx.x >> 4;
    const int chunk = blockIdx.x & 15;
    const int t = threadIdx.x;
    const float* kh = kmat + (size_t)head * NN * DD;

    // per-thread projection row m=t in registers
    float pr[64];
#pragma unroll
    for (int j4 = 0; j4 < 16; ++j4) {
        float4 v = ((const float4*)(proj + (size_t)t * 64))[j4];
        pr[4*j4+0] = v.x; pr[4*j4+1] = v.y; pr[4*j4+2] = v.z; pr[4*j4+3] = v.w;
    }

    __shared__ float rows[8 * 64];
    __shared__ float red[256];
    float maxv = -3.4e38f;
    const int base = chunk * 256;

    for (int nr = 0; nr < 256; nr += 8) {
        __syncthreads();
        rows[t]       = kh[(size_t)(base + nr) * 64 + t]       * NORMALIZER;
        rows[t + 256] = kh[(size_t)(base + nr) * 64 + t + 256] * NORMALIZER;
        __syncthreads();
        if (t < 8) {
            float s = 0.f;
#pragma unroll
            for (int j = 0; j < 64; ++j) { float x = rows[t*64+j]; s += x*x; }
            diagK[head * NN + base + nr + t] = 0.5f * s;
        }
#pragma unroll
        for (int r = 0; r < 8; ++r) {
            float dot = 0.f;
#pragma unroll
            for (int j = 0; j < 64; ++j) dot += pr[j] * rows[r*64+j];
            maxv = fmaxf(maxv, dot);
        }
    }
    red[t] = maxv;
    __syncthreads();
    for (int s = 128; s > 0; s >>= 1) {
        if (t < s) red[t] = fmaxf(red[t], red[t + s]);
        __syncthreads();
    }
    if (t == 0) atomicMax(mkKey + head, fkey(red[0]));
}

// ---------------- K2: context partials ----------------
// grid = BH*4 blocks, 256 threads. thread t <-> m=t. 1024 rows per block.
// partial layout: [blk][e(65)][m(256)]
__global__ __launch_bounds__(256, 2) void k2_context(
        const float* __restrict__ kmat, const float* __restrict__ vmat,
        const float* __restrict__ proj, const unsigned* __restrict__ mkKey,
        const float* __restrict__ diagK, float* __restrict__ partial) {
    const int head = blockIdx.x >> 2;
    const int chunk = blockIdx.x & 3;
    const int t = threadIdx.x;
    const float* kh = kmat + (size_t)head * NN * DD;
    const float* vh = vmat + (size_t)head * NN * DD;
    const float MK = funkey(mkKey[head]);

    float pr[64];
#pragma unroll
    for (int j4 = 0; j4 < 16; ++j4) {
        float4 v = ((const float4*)(proj + (size_t)t * 64))[j4];
        pr[4*j4+0] = v.x; pr[4*j4+1] = v.y; pr[4*j4+2] = v.z; pr[4*j4+3] = v.w;
    }
    float acc[65];
#pragma unroll
    for (int e = 0; e < 65; ++e) acc[e] = 0.f;

    __shared__ float krows[512];
    __shared__ float vrows[512];
    __shared__ float dg[8];
    const int base = chunk * 1024;

    for (int nr = 0; nr < 1024; nr += 8) {
        __syncthreads();
        krows[t]       = kh[(size_t)(base + nr) * 64 + t]       * NORMALIZER;
        krows[t + 256] = kh[(size_t)(base + nr) * 64 + t + 256] * NORMALIZER;
        vrows[t]       = vh[(size_t)(base + nr) * 64 + t];
        vrows[t + 256] = vh[(size_t)(base + nr) * 64 + t + 256];
        if (t < 8) dg[t] = diagK[head * NN + base + nr + t];
        __syncthreads();
#pragma unroll
        for (int r = 0; r < 8; ++r) {
            float dot = 0.f;
#pragma unroll
            for (int j = 0; j < 64; ++j) dot += pr[j] * krows[r*64+j];
            float kp = RATIO * (__expf(dot - dg[r] - MK) + EPSV);
            acc[64] += kp;
#pragma unroll
            for (int e = 0; e < 64; ++e) acc[e] += kp * vrows[r*64+e];
        }
    }
    float* P = partial + (size_t)blockIdx.x * 65 * 256;
    for (int e = 0; e < 65; ++e) P[e * 256 + t] = acc[e];
}

// ---------------- K2b: reduce partials -> ctx [head][m][e], ksum [head][m] --
__global__ void k2b_reduce(const float* __restrict__ partial,
                           float* __restrict__ ctx, float* __restrict__ ksum) {
    int idx = blockIdx.x * 256 + threadIdx.x;
    if (idx >= BH * 65 * 256) return;
    int m = idx & 255;
    int e = (idx >> 8) % 65;
    int head = idx / (65 * 256);
    float s = 0.f;
#pragma unroll
    for (int c = 0; c < 4; ++c)
        s += partial[(((size_t)(head * 4 + c) * 65) + e) * 256 + m];
    if (e < 64) ctx[((size_t)head * 256 + m) * 64 + e] = s;
    else        ksum[head * 256 + m] = s;
}

// ---------------- K3: q features + output ----------------
// grid = BH*16 blocks, 256 threads, thread t <-> row n = chunk*256+t.
__global__ __launch_bounds__(256, 2) void k3_out(
        const float* __restrict__ qmat, const float* __restrict__ proj,
        const float* __restrict__ ctx, const float* __restrict__ ksum,
        float* __restrict__ out) {
    const int head = blockIdx.x >> 4;
    const int chunk = blockIdx.x & 15;
    const int t = threadIdx.x;
    const int n = chunk * 256 + t;
    const float* qg = qmat + ((size_t)head * NN + n) * 64;

    __shared__ float projs[MM * DD]; // 64 KB, broadcast reads
    for (int i = t; i < MM * DD; i += 256) projs[i] = proj[i];

    float qr[64];
    float diag = 0.f;
#pragma unroll
    for (int j4 = 0; j4 < 16; ++j4) {
        float4 v = ((const float4*)qg)[j4];
        qr[4*j4+0] = v.x * NORMALIZER; qr[4*j4+1] = v.y * NORMALIZER;
        qr[4*j4+2] = v.z * NORMALIZER; qr[4*j4+3] = v.w * NORMALIZER;
    }
#pragma unroll
    for (int j = 0; j < 64; ++j) diag += qr[j] * qr[j];
    diag *= 0.5f;
    __syncthreads();

    // pass 1: row max of q_dash
    float mx = -3.4e38f;
    for (int mm = 0; mm < 256; ++mm) {
        float dot = 0.f;
#pragma unroll
        for (int j = 0; j < 64; ++j) dot += qr[j] * projs[mm*64+j];
        mx = fmaxf(mx, dot);
    }

    // pass 2: features, denominator, output accumulation
    const float* ch = ctx + (size_t)head * 256 * 64;
    const float* ks = ksum + head * 256;
    float acc[64];
#pragma unroll
    for (int e = 0; e < 64; ++e) acc[e] = 0.f;
    float denom = 0.f;
    for (int mm = 0; mm < 256; ++mm) {
        float dot = 0.f;
#pragma unroll
        for (int j = 0; j < 64; ++j) dot += qr[j] * projs[mm*64+j];
        float qp = RATIO * (__expf(dot - diag - mx) + EPSV);
        denom += qp * ks[mm];
#pragma unroll
        for (int e = 0; e < 64; ++e) acc[e] += qp * ch[mm*64+e];
    }
    float dinv = 1.0f / denom;
    float* og = out + ((size_t)head * NN + n) * 64;
#pragma unroll
    for (int e4 = 0; e4 < 16; ++e4) {
        float4 v;
        v.x = acc[4*e4+0] * dinv; v.y = acc[4*e4+1] * dinv;
        v.z = acc[4*e4+2] * dinv; v.w = acc[4*e4+3] * dinv;
        ((float4*)og)[e4] = v;
    }
}

extern "C" void kernel_launch(void* const* d_in, const int* in_sizes, int n_in,
                              void* d_out, int out_size, void* d_ws, size_t ws_size,
                              hipStream_t stream) {
    const float* q    = (const float*)d_in[0];
    const float* k    = (const float*)d_in[1];
    const float* v    = (const float*)d_in[2];
    const float* proj = (const float*)d_in[3];
    float* out = (float*)d_out;

    // workspace layout (floats)
    float* base = (float*)d_ws;
    unsigned* mkKey = (unsigned*)d_ws;                 // 128 uints
    float* diagK   = base + 128;                       // 128*4096
    float* partial = diagK + (size_t)BH * NN;          // 512*65*256
    float* ctx     = partial + (size_t)BH * 4 * 65 * 256; // 128*256*64
    float* ksum    = ctx + (size_t)BH * 256 * 64;      // 128*256

    hipMemsetAsync(d_ws, 0, 128 * sizeof(unsigned), stream);

    k1_maxdiag<<<BH * 16, 256, 0, stream>>>(k, proj, mkKey, diagK);
    k2_context<<<BH * 4, 256, 0, stream>>>(k, v, proj, mkKey, diagK, partial);
    k2b_reduce<<<(BH * 65 * 256 + 255) / 256, 256, 0, stream>>>(partial, ctx, ksum);
    k3_out<<<BH * 16, 256, 0, stream>>>(q, proj, ctx, ksum, out);
}

// Round 2
// 876.182 us; speedup vs baseline: 3.6519x; 3.6519x over previous
//
#include <hip/hip_runtime.h>

// Performer FAVOR+ linear attention, MFMA bf16 hi/lo-split implementation.
// b*h=128 heads, n=4096, d=64, m=256, fp32 in/out.

#define BH 128
#define NN 4096
#define DD 64
#define MM 256
#define NORM 0.35355339059327373f   // 64^-0.25
#define EPS 1e-4f

typedef unsigned short u16;
typedef __attribute__((ext_vector_type(8))) short bfrag;   // 8 x bf16
typedef __attribute__((ext_vector_type(4))) float ffrag;   // 4 x f32
#define MFMA16(A,B,C) __builtin_amdgcn_mfma_f32_16x16x32_bf16(A,B,C,0,0,0)

__device__ __forceinline__ float u2f(u16 h){ return __uint_as_float(((unsigned)h)<<16); }
__device__ __forceinline__ void splitf(float x, u16 &h, u16 &l){
    unsigned uh = __float_as_uint(x) & 0xffff0000u;
    h = (u16)(uh >> 16);
    float r = x - __uint_as_float(uh);
    l = (u16)(__float_as_uint(r) >> 16);
}

// ---------------- P0a: split projection ----------------
__global__ void p0_proj(const float* __restrict__ proj, u16* __restrict__ phi, u16* __restrict__ plo){
    int idx = blockIdx.x*256 + threadIdx.x;   // 16384 total
    u16 h,l; splitf(proj[idx], h, l);
    phi[idx] = h; plo[idx] = l;
}

// ---------------- P0b: V -> VT (hi/lo) + vsum ----------------
// grid BH*64; block handles [64 n][64 e] tile of one head.
__global__ __launch_bounds__(256) void p0_vt(const float* __restrict__ vin,
        u16* __restrict__ vthi, u16* __restrict__ vtlo, float* __restrict__ vsum){
    int head = blockIdx.x >> 6;
    int n0 = (blockIdx.x & 63) * 64;
    int t = threadIdx.x;
    __shared__ float tile[64][65];
    {
        int row = t >> 2, c0 = (t & 3) * 16;
        const float* src = vin + ((size_t)head*NN + n0 + row)*64 + c0;
        #pragma unroll
        for (int i=0;i<4;++i){
            float4 x = *(const float4*)(src + i*4);
            tile[row][c0+i*4+0]=x.x; tile[row][c0+i*4+1]=x.y;
            tile[row][c0+i*4+2]=x.z; tile[row][c0+i*4+3]=x.w;
        }
    }
    __syncthreads();
    {
        int e = t >> 2, nq = (t & 3) * 16;
        float s = 0.f;
        unsigned ph[8], pl[8];
        #pragma unroll
        for (int jj=0;jj<8;++jj){
            float x0 = tile[nq+jj*2+0][e];
            float x1 = tile[nq+jj*2+1][e];
            s += x0 + x1;
            u16 h0,l0,h1,l1; splitf(x0,h0,l0); splitf(x1,h1,l1);
            ph[jj] = (unsigned)h0 | ((unsigned)h1<<16);
            pl[jj] = (unsigned)l0 | ((unsigned)l1<<16);
        }
        size_t base = ((size_t)head*64 + e)*NN + n0 + nq;
        uint4 a0; a0.x=ph[0]; a0.y=ph[1]; a0.z=ph[2]; a0.w=ph[3];
        uint4 a1; a1.x=ph[4]; a1.y=ph[5]; a1.z=ph[6]; a1.w=ph[7];
        uint4 b0; b0.x=pl[0]; b0.y=pl[1]; b0.z=pl[2]; b0.w=pl[3];
        uint4 b1; b1.x=pl[4]; b1.y=pl[5]; b1.z=pl[6]; b1.w=pl[7];
        *(uint4*)(vthi + base)     = a0;
        *(uint4*)(vthi + base + 8) = a1;
        *(uint4*)(vtlo + base)     = b0;
        *(uint4*)(vtlo + base + 8) = b1;
        s += __shfl_xor(s, 1);
        s += __shfl_xor(s, 2);
        if ((t & 3) == 0) atomicAdd(vsum + head*64 + e, s);
    }
}

// ---------------- KC: K-side dash GEMM -> exp (flash max) -> ctx^T GEMM ----------------
// grid 1024 = 128 heads x 8 chunks (512 n each). 256 thr = 4 waves.
__global__ __launch_bounds__(256,2) void kc_kernel(
        const float* __restrict__ kin, const u16* __restrict__ phi, const u16* __restrict__ plo,
        const u16* __restrict__ vthi, const u16* __restrict__ vtlo,
        float* __restrict__ ctxPart, float* __restrict__ mbArr)
{
    const int blk  = blockIdx.x;
    const int head = blk >> 3;
    const int n0   = (blk & 7) * 512;
    const int t    = threadIdx.x;
    const int w    = t >> 6;
    const int lane = t & 63;
    const int qd   = lane >> 4;
    const int li   = lane & 15;

    __shared__ __attribute__((aligned(16))) u16 knh[32*64], knl[32*64];
    __shared__ __attribute__((aligned(16))) u16 bsh[256*32], bsl[256*32];
    __shared__ float diag_s[32];
    __shared__ float wmax[4];

    // projection B-frags for this wave's m-quarter (held in regs)
    bfrag pf[4][2][2];
    #pragma unroll
    for (int mt=0;mt<4;++mt){
        int m = w*64 + mt*16 + li;
        #pragma unroll
        for (int ks=0;ks<2;++ks){
            pf[mt][ks][0] = *(const bfrag*)(phi + m*64 + ks*32 + qd*8);
            pf[mt][ks][1] = *(const bfrag*)(plo + m*64 + ks*32 + qd*8);
        }
    }

    ffrag acc[4][4];
    #pragma unroll
    for (int et=0;et<4;++et)
        #pragma unroll
        for (int mt=0;mt<4;++mt){ ffrag z = {0.f,0.f,0.f,0.f}; acc[et][mt] = z; }
    float ks[4] = {0.f,0.f,0.f,0.f};
    float M = -3.0e38f;

    const float* kg = kin + ((size_t)head*NN + n0)*64;

    for (int sub=0; sub<16; ++sub){
        // ---- stage Kn subtile [32 n][64 d], swizzled, + diag via shfl
        {
            int row = t >> 3;
            int g   = t & 7;
            const float* src = kg + (size_t)(sub*32 + row)*64 + g*8;
            float4 x0 = *(const float4*)(src);
            float4 x1 = *(const float4*)(src + 4);
            float xs[8] = {x0.x,x0.y,x0.z,x0.w,x1.x,x1.y,x1.z,x1.w};
            bfrag hv, lv;
            float ss = 0.f;
            #pragma unroll
            for (int j=0;j<8;++j){
                float xn = xs[j]*NORM;
                ss += xn*xn;
                u16 hh,ll; splitf(xn,hh,ll);
                hv[j] = (short)hh; lv[j] = (short)ll;
            }
            int gs = g ^ (row & 7);
            *(bfrag*)(knh + row*64 + gs*8) = hv;
            *(bfrag*)(knl + row*64 + gs*8) = lv;
            ss += __shfl_xor(ss, 1);
            ss += __shfl_xor(ss, 2);
            ss += __shfl_xor(ss, 4);
            if ((t & 7) == 0) diag_s[row] = 0.5f*ss;
        }
        __syncthreads();   // knh/knl/diag ready; prev Bs reads done (prev iter barrier)

        // ---- GEMM1: dash[32 n][256 m] (this wave: its m-quarter)
        ffrag d1[2][4];
        #pragma unroll
        for (int nt=0;nt<2;++nt)
            #pragma unroll
            for (int mt=0;mt<4;++mt){ ffrag z = {0.f,0.f,0.f,0.f}; d1[nt][mt] = z; }
        #pragma unroll
        for (int nt=0;nt<2;++nt){
            int n = nt*16 + li;
            bfrag ah[2], al[2];
            #pragma unroll
            for (int kss=0;kss<2;++kss){
                int gp = (kss*4 + qd) ^ (n & 7);
                ah[kss] = *(const bfrag*)(knh + n*64 + gp*8);
                al[kss] = *(const bfrag*)(knl + n*64 + gp*8);
            }
            #pragma unroll
            for (int mt=0;mt<4;++mt){
                #pragma unroll
                for (int kss=0;kss<2;++kss){
                    d1[nt][mt] = MFMA16(ah[kss], pf[mt][kss][0], d1[nt][mt]);
                    d1[nt][mt] = MFMA16(ah[kss], pf[mt][kss][1], d1[nt][mt]);
                    d1[nt][mt] = MFMA16(al[kss], pf[mt][kss][0], d1[nt][mt]);
                }
            }
        }

        // ---- subtile max (block-wide)
        float mx = -3.0e38f;
        #pragma unroll
        for (int nt=0;nt<2;++nt)
            #pragma unroll
            for (int mt=0;mt<4;++mt)
                #pragma unroll
                for (int rg=0;rg<4;++rg) mx = fmaxf(mx, d1[nt][mt][rg]);
        mx = fmaxf(mx, __shfl_xor(mx, 1));
        mx = fmaxf(mx, __shfl_xor(mx, 2));
        mx = fmaxf(mx, __shfl_xor(mx, 4));
        mx = fmaxf(mx, __shfl_xor(mx, 8));
        mx = fmaxf(mx, __shfl_xor(mx, 16));
        mx = fmaxf(mx, __shfl_xor(mx, 32));
        if (lane == 0) wmax[w] = mx;
        __syncthreads();
        float Ms = fmaxf(fmaxf(wmax[0],wmax[1]), fmaxf(wmax[2],wmax[3]));
        float Mn = fmaxf(M, Ms);
        float r  = __expf(M - Mn);   // 0 on first subtile
        M = Mn;
        #pragma unroll
        for (int mt=0;mt<4;++mt) ks[mt] *= r;
        #pragma unroll
        for (int et=0;et<4;++et)
            #pragma unroll
            for (int mt=0;mt<4;++mt)
                #pragma unroll
                for (int rg=0;rg<4;++rg) acc[et][mt][rg] *= r;

        // ---- features -> Bs[m 256][n 32] (transposed, swizzled), + ksum partials
        float sl[4] = {0.f,0.f,0.f,0.f};
        #pragma unroll
        for (int nt=0;nt<2;++nt){
            float d4[4];
            #pragma unroll
            for (int rg=0;rg<4;++rg) d4[rg] = diag_s[nt*16 + qd*4 + rg];
            #pragma unroll
            for (int mt=0;mt<4;++mt){
                int m = w*64 + mt*16 + li;
                u16 h4[4], l4[4];
                #pragma unroll
                for (int rg=0;rg<4;++rg){
                    float f = __expf(d1[nt][mt][rg] - d4[rg] - M);
                    sl[mt] += f;
                    splitf(f, h4[rg], l4[rg]);
                }
                int g  = nt*2 + (qd>>1);
                int gp = g ^ ((m>>1)&3);
                int off = m*32 + gp*8 + (qd&1)*4;
                *(ushort4*)(bsh + off) = make_ushort4(h4[0],h4[1],h4[2],h4[3]);
                *(ushort4*)(bsl + off) = make_ushort4(l4[0],l4[1],l4[2],l4[3]);
            }
        }
        #pragma unroll
        for (int mt=0;mt<4;++mt){
            float v = sl[mt];
            v += __shfl_xor(v, 16);
            v += __shfl_xor(v, 32);
            ks[mt] += v;
        }
        __syncthreads();   // Bs ready

        // ---- ctx^T GEMM: acc[e][m] += VT[e][n-chunk] * feat[m][n-chunk]
        bfrag bh[4], bl[4];
        #pragma unroll
        for (int mt=0;mt<4;++mt){
            int m = w*64 + mt*16 + li;
            int gp = qd ^ ((m>>1)&3);
            bh[mt] = *(const bfrag*)(bsh + m*32 + gp*8);
            bl[mt] = *(const bfrag*)(bsl + m*32 + gp*8);
        }
        #pragma unroll
        for (int et=0;et<4;++et){
            int e = et*16 + li;
            size_t vb = ((size_t)head*64 + e)*NN + n0 + sub*32 + qd*8;
            bfrag avh = *(const bfrag*)(vthi + vb);
            bfrag avl = *(const bfrag*)(vtlo + vb);
            #pragma unroll
            for (int mt=0;mt<4;++mt){
                acc[et][mt] = MFMA16(avh, bh[mt], acc[et][mt]);
                acc[et][mt] = MFMA16(avh, bl[mt], acc[et][mt]);
                acc[et][mt] = MFMA16(avl, bh[mt], acc[et][mt]);
            }
        }
        __syncthreads();   // ctx reads done before next feat overwrite
    }

    // ---- epilogue: partials [blk][65][256] (row 64 = ksum)
    float* P = ctxPart + (size_t)blk * (65*256);
    #pragma unroll
    for (int et=0;et<4;++et)
        #pragma unroll
        for (int mt=0;mt<4;++mt)
            #pragma unroll
            for (int rg=0;rg<4;++rg){
                int e = et*16 + qd*4 + rg;
                int m = w*64 + mt*16 + li;
                P[e*256 + m] = acc[et][mt][rg];
            }
    if (qd == 0){
        #pragma unroll
        for (int mt=0;mt<4;++mt) P[64*256 + w*64 + mt*16 + li] = ks[mt];
    }
    if (t == 0) mbArr[blk] = M;
}

// ---------------- kred: combine 8 scaled partials -> ctxT hi/lo + ksum ----------------
// grid BH*65; block (head, e); thread = m.
__global__ __launch_bounds__(256) void kred(const float* __restrict__ ctxPart,
        const float* __restrict__ mbArr, const float* __restrict__ vsum,
        u16* __restrict__ ctxh, u16* __restrict__ ctxl, float* __restrict__ ksumG){
    int head = blockIdx.x / 65;
    int e = blockIdx.x % 65;
    int m = threadIdx.x;
    float mb[8];
    float mk = -3.0e38f;
    #pragma unroll
    for (int c=0;c<8;++c){ mb[c] = mbArr[head*8+c]; mk = fmaxf(mk, mb[c]); }
    float s = 0.f;
    #pragma unroll
    for (int c=0;c<8;++c){
        float sc = __expf(mb[c] - mk);
        s += sc * ctxPart[((size_t)(head*8+c)*65 + e)*256 + m];
    }
    if (e == 64){
        ksumG[head*256 + m] = s + 4096.0f*EPS;
    } else {
        float val = s + EPS * vsum[head*64 + e];
        u16 h,l; splitf(val,h,l);
        ctxh[((size_t)head*64 + e)*256 + m] = h;
        ctxl[((size_t)head*64 + e)*256 + m] = l;
    }
}

// ---------------- K3: Q-side dash GEMM -> exp -> output GEMM ----------------
// grid BH*64 (64 q-rows per block). 256 thr = 4 waves.
__global__ __launch_bounds__(256,2) void k3_kernel(
        const float* __restrict__ qin, const u16* __restrict__ phi, const u16* __restrict__ plo,
        const u16* __restrict__ ctxh, const u16* __restrict__ ctxl,
        const float* __restrict__ ksumG, float* __restrict__ out)
{
    const int head = blockIdx.x >> 6;
    const int n0   = (blockIdx.x & 63) * 64;
    const int t    = threadIdx.x;
    const int w    = t >> 6;
    const int lane = t & 63;
    const int qd   = lane >> 4;
    const int li   = lane & 15;

    __shared__ __attribute__((aligned(16))) u16 SM[32768];  // 64KB: qn staging aliased by feat hi/lo
    u16* qnh = SM;            // [64][64]  (phase 1)
    u16* qnl = SM + 4096;
    u16* fh  = SM;            // [64][256] (phase 2+)
    u16* fl  = SM + 16384;
    __shared__ float diagq[64], drm[64], dinvs[64], ksums[256], wred[256];

    // stage Qn [64][64] hi/lo (swizzled) + diagq; load ksums
    ksums[t] = ksumG[head*256 + t];
    {
        int row = t >> 2;
        const float* src = qin + ((size_t)head*NN + n0 + row)*64 + (t&3)*16;
        float ss = 0.f;
        #pragma unroll
        for (int gi=0; gi<2; ++gi){
            int g = (t&3)*2 + gi;
            float4 x0 = *(const float4*)(src + gi*8);
            float4 x1 = *(const float4*)(src + gi*8 + 4);
            float xs[8] = {x0.x,x0.y,x0.z,x0.w,x1.x,x1.y,x1.z,x1.w};
            bfrag hv, lv;
            #pragma unroll
            for (int j=0;j<8;++j){
                float xn = xs[j]*NORM;
                ss += xn*xn;
                u16 hh,ll; splitf(xn,hh,ll);
                hv[j] = (short)hh; lv[j] = (short)ll;
            }
            int gs = g ^ (row & 7);
            *(bfrag*)(qnh + row*64 + gs*8) = hv;
            *(bfrag*)(qnl + row*64 + gs*8) = lv;
        }
        ss += __shfl_xor(ss, 1);
        ss += __shfl_xor(ss, 2);
        if ((t&3) == 0) diagq[row] = 0.5f*ss;
    }

    // P-frags
    bfrag pf[4][2][2];
    #pragma unroll
    for (int mt=0;mt<4;++mt){
        int m = w*64 + mt*16 + li;
        #pragma unroll
        for (int kss=0;kss<2;++kss){
            pf[mt][kss][0] = *(const bfrag*)(phi + m*64 + kss*32 + qd*8);
            pf[mt][kss][1] = *(const bfrag*)(plo + m*64 + kss*32 + qd*8);
        }
    }
    __syncthreads();

    // GEMM1: qdash[64 n][256 m], wave = m-quarter
    ffrag d1[4][4];
    #pragma unroll
    for (int nt=0;nt<4;++nt)
        #pragma unroll
        for (int mt=0;mt<4;++mt){ ffrag z = {0.f,0.f,0.f,0.f}; d1[nt][mt] = z; }
    #pragma unroll
    for (int nt=0;nt<4;++nt){
        int n = nt*16 + li;
        bfrag ah[2], al[2];
        #pragma unroll
        for (int kss=0;kss<2;++kss){
            int gp = (kss*4 + qd) ^ (n & 7);
            ah[kss] = *(const bfrag*)(qnh + n*64 + gp*8);
            al[kss] = *(const bfrag*)(qnl + n*64 + gp*8);
        }
        #pragma unroll
        for (int mt=0;mt<4;++mt){
            #pragma unroll
            for (int kss=0;kss<2;++kss){
                d1[nt][mt] = MFMA16(ah[kss], pf[mt][kss][0], d1[nt][mt]);
                d1[nt][mt] = MFMA16(ah[kss], pf[mt][kss][1], d1[nt][mt]);
                d1[nt][mt] = MFMA16(al[kss], pf[mt][kss][0], d1[nt][mt]);
            }
        }
    }

    // per-row max over this wave's m-quarter, then cross-wave
    #pragma unroll
    for (int nt=0;nt<4;++nt){
        #pragma unroll
        for (int rg=0;rg<4;++rg){
            float v = fmaxf(fmaxf(d1[nt][0][rg], d1[nt][1][rg]),
                            fmaxf(d1[nt][2][rg], d1[nt][3][rg]));
            v = fmaxf(v, __shfl_xor(v, 1));
            v = fmaxf(v, __shfl_xor(v, 2));
            v = fmaxf(v, __shfl_xor(v, 4));
            v = fmaxf(v, __shfl_xor(v, 8));
            if (li == 0) wred[w*64 + nt*16 + qd*4 + rg] = v;
        }
    }
    __syncthreads();
    if (t < 64){
        float rm = fmaxf(fmaxf(wred[t], wred[64+t]), fmaxf(wred[128+t], wred[192+t]));
        drm[t] = diagq[t] + rm;
    }
    __syncthreads();

    // features (with eps) -> fh/fl [n][256] swizzled   (overwrites qn staging)
    #pragma unroll
    for (int nt=0;nt<4;++nt){
        float dr4[4];
        #pragma unroll
        for (int rg=0;rg<4;++rg) dr4[rg] = drm[nt*16 + qd*4 + rg];
        #pragma unroll
        for (int mt=0;mt<4;++mt){
            int m = w*64 + mt*16 + li;
            #pragma unroll
            for (int rg=0;rg<4;++rg){
                int n = nt*16 + qd*4 + rg;
                float f = __expf(d1[nt][mt][rg] - dr4[rg]) + EPS;
                u16 hh,ll; splitf(f,hh,ll);
                int idx = n*256 + (((m>>3) ^ (n&7))*8) + (m&7);
                fh[idx] = hh; fl[idx] = ll;
            }
        }
    }
    __syncthreads();

    // denom: thread t -> row t>>2, m-segment (t&3)*64
    {
        int row = t >> 2, seg = t & 3;
        float s = 0.f;
        #pragma unroll
        for (int g=0; g<8; ++g){
            int gl = seg*8 + g;
            int gp = gl ^ (row & 7);
            bfrag hvv = *(const bfrag*)(fh + row*256 + gp*8);
            bfrag lvv = *(const bfrag*)(fl + row*256 + gp*8);
            #pragma unroll
            for (int j=0;j<8;++j){
                float f = u2f((u16)hvv[j]) + u2f((u16)lvv[j]);
                s += f * ksums[gl*8 + j];
            }
        }
        wred[t] = s;
    }
    __syncthreads();
    if (t < 64){
        float dsum = wred[4*t] + wred[4*t+1] + wred[4*t+2] + wred[4*t+3];
        dinvs[t] = 1.0f / dsum;
    }
    __syncthreads();

    // GEMM2: out[n][e] = sum_m feat[n][m] * ctxT[e][m]; wave = n-tile w
    ffrag a2[4];
    #pragma unroll
    for (int et=0;et<4;++et){ ffrag z = {0.f,0.f,0.f,0.f}; a2[et] = z; }
    const u16* cbh = ctxh + (size_t)head*64*256;
    const u16* cbl = ctxl + (size_t)head*64*256;
    int n2 = w*16 + li;
    #pragma unroll
    for (int ksm=0; ksm<8; ++ksm){
        int gp = (ksm*4 + qd) ^ (n2 & 7);
        bfrag ah2 = *(const bfrag*)(fh + n2*256 + gp*8);
        bfrag al2 = *(const bfrag*)(fl + n2*256 + gp*8);
        #pragma unroll
        for (int et=0;et<4;++et){
            int e = et*16 + li;
            bfrag ch = *(const bfrag*)(cbh + e*256 + ksm*32 + qd*8);
            bfrag cl = *(const bfrag*)(cbl + e*256 + ksm*32 + qd*8);
            a2[et] = MFMA16(ah2, ch, a2[et]);
            a2[et] = MFMA16(ah2, cl, a2[et]);
            a2[et] = MFMA16(al2, ch, a2[et]);
        }
    }

    float dvr[4];
    #pragma unroll
    for (int rg=0;rg<4;++rg) dvr[rg] = dinvs[w*16 + qd*4 + rg];
    float* og = out + ((size_t)head*NN + n0 + w*16)*64;
    #pragma unroll
    for (int et=0;et<4;++et)
        #pragma unroll
        for (int rg=0;rg<4;++rg)
            og[(qd*4+rg)*64 + et*16 + li] = a2[et][rg] * dvr[rg];
}

extern "C" void kernel_launch(void* const* d_in, const int* in_sizes, int n_in,
                              void* d_out, int out_size, void* d_ws, size_t ws_size,
                              hipStream_t stream) {
    const float* q    = (const float*)d_in[0];
    const float* k    = (const float*)d_in[1];
    const float* v    = (const float*)d_in[2];
    const float* proj = (const float*)d_in[3];
    float* out = (float*)d_out;

    char* wp = (char*)d_ws;
    u16* phi     = (u16*)wp;  wp += (size_t)MM*DD*2;
    u16* plo     = (u16*)wp;  wp += (size_t)MM*DD*2;
    u16* vthi    = (u16*)wp;  wp += (size_t)BH*64*NN*2;
    u16* vtlo    = (u16*)wp;  wp += (size_t)BH*64*NN*2;
    float* vsum  = (float*)wp; wp += (size_t)BH*64*4;
    float* mbArr = (float*)wp; wp += (size_t)1024*4;
    float* ctxPart = (float*)wp; wp += (size_t)1024*65*256*4;
    u16* ctxh    = (u16*)wp;  wp += (size_t)BH*64*256*2;
    u16* ctxl    = (u16*)wp;  wp += (size_t)BH*64*256*2;
    float* ksumG = (float*)wp; wp += (size_t)BH*256*4;

    hipMemsetAsync(vsum, 0, (size_t)BH*64*4, stream);
    p0_proj<<<64, 256, 0, stream>>>(proj, phi, plo);
    p0_vt<<<BH*64, 256, 0, stream>>>(v, vthi, vtlo, vsum);
    kc_kernel<<<1024, 256, 0, stream>>>(k, phi, plo, vthi, vtlo, ctxPart, mbArr);
    kred<<<BH*65, 256, 0, stream>>>(ctxPart, mbArr, vsum, ctxh, ctxl, ksumG);
    k3_kernel<<<BH*64, 256, 0, stream>>>(q, phi, plo, ctxh, ctxl, ksumG, out);
}

// Round 3
// 705.869 us; speedup vs baseline: 4.5330x; 1.2413x over previous
//
#include <hip/hip_runtime.h>

// Performer FAVOR+ linear attention, MFMA bf16 hi/lo-split implementation.
// b*h=128 heads, n=4096, d=64, m=256, fp32 in/out.

#define BH 128
#define NN 4096
#define DD 64
#define MM 256
#define NORM 0.35355339059327373f   // 64^-0.25
#define EPS 1e-4f

typedef unsigned short u16;
typedef __attribute__((ext_vector_type(8))) short bfrag;   // 8 x bf16
typedef __attribute__((ext_vector_type(4))) float ffrag;   // 4 x f32
#define MFMA16(A,B,C) __builtin_amdgcn_mfma_f32_16x16x32_bf16(A,B,C,0,0,0)

__device__ __forceinline__ float u2f(u16 h){ return __uint_as_float(((unsigned)h)<<16); }
__device__ __forceinline__ void splitf(float x, u16 &h, u16 &l){
    unsigned uh = __float_as_uint(x) & 0xffff0000u;
    h = (u16)(uh >> 16);
    float r = x - __uint_as_float(uh);
    l = (u16)(__float_as_uint(r) >> 16);
}

// ---------------- P0a: split projection ----------------
__global__ void p0_proj(const float* __restrict__ proj, u16* __restrict__ phi, u16* __restrict__ plo){
    int idx = blockIdx.x*256 + threadIdx.x;   // 16384 total
    u16 h,l; splitf(proj[idx], h, l);
    phi[idx] = h; plo[idx] = l;
}

// ---------------- P0b: V -> VT (hi/lo) + vsum ----------------
__global__ __launch_bounds__(256) void p0_vt(const float* __restrict__ vin,
        u16* __restrict__ vthi, u16* __restrict__ vtlo, float* __restrict__ vsum){
    int head = blockIdx.x >> 6;
    int n0 = (blockIdx.x & 63) * 64;
    int t = threadIdx.x;
    __shared__ float tile[64][65];
    {
        int row = t >> 2, c0 = (t & 3) * 16;
        const float* src = vin + ((size_t)head*NN + n0 + row)*64 + c0;
        #pragma unroll
        for (int i=0;i<4;++i){
            float4 x = *(const float4*)(src + i*4);
            tile[row][c0+i*4+0]=x.x; tile[row][c0+i*4+1]=x.y;
            tile[row][c0+i*4+2]=x.z; tile[row][c0+i*4+3]=x.w;
        }
    }
    __syncthreads();
    {
        int e = t >> 2, nq = (t & 3) * 16;
        float s = 0.f;
        unsigned ph[8], pl[8];
        #pragma unroll
        for (int jj=0;jj<8;++jj){
            float x0 = tile[nq+jj*2+0][e];
            float x1 = tile[nq+jj*2+1][e];
            s += x0 + x1;
            u16 h0,l0,h1,l1; splitf(x0,h0,l0); splitf(x1,h1,l1);
            ph[jj] = (unsigned)h0 | ((unsigned)h1<<16);
            pl[jj] = (unsigned)l0 | ((unsigned)l1<<16);
        }
        size_t base = ((size_t)head*64 + e)*NN + n0 + nq;
        uint4 a0; a0.x=ph[0]; a0.y=ph[1]; a0.z=ph[2]; a0.w=ph[3];
        uint4 a1; a1.x=ph[4]; a1.y=ph[5]; a1.z=ph[6]; a1.w=ph[7];
        uint4 b0; b0.x=pl[0]; b0.y=pl[1]; b0.z=pl[2]; b0.w=pl[3];
        uint4 b1; b1.x=pl[4]; b1.y=pl[5]; b1.z=pl[6]; b1.w=pl[7];
        *(uint4*)(vthi + base)     = a0;
        *(uint4*)(vthi + base + 8) = a1;
        *(uint4*)(vtlo + base)     = b0;
        *(uint4*)(vtlo + base + 8) = b1;
        s += __shfl_xor(s, 1);
        s += __shfl_xor(s, 2);
        if ((t & 3) == 0) atomicAdd(vsum + head*64 + e, s);
    }
}

// ---------------- KC: K-side dash GEMM -> exp (flash max) -> ctx^T GEMM ----------------
// grid 1024 = 128 heads x 8 chunks (512 n each). 256 thr = 4 waves.
__global__ __launch_bounds__(256) __attribute__((amdgpu_waves_per_eu(2,2)))
void kc_kernel(
        const float* __restrict__ kin, const u16* __restrict__ phi, const u16* __restrict__ plo,
        const u16* __restrict__ vthi, const u16* __restrict__ vtlo,
        float* __restrict__ ctxPart, float* __restrict__ mbArr)
{
    const int blk  = blockIdx.x;
    const int head = blk >> 3;
    const int n0   = (blk & 7) * 512;
    const int t    = threadIdx.x;
    const int w    = t >> 6;
    const int lane = t & 63;
    const int qd   = lane >> 4;
    const int li   = lane & 15;

    __shared__ __attribute__((aligned(16))) u16 knh[32*64], knl[32*64];
    __shared__ __attribute__((aligned(16))) u16 bsh[256*32], bsl[256*32];
    __shared__ float diag_s[32];
    __shared__ float wmax[4];

    // projection B-frags for this wave's m-quarter (held in regs)
    bfrag pf[4][2][2];
    #pragma unroll
    for (int mt=0;mt<4;++mt){
        int m = w*64 + mt*16 + li;
        #pragma unroll
        for (int ks=0;ks<2;++ks){
            pf[mt][ks][0] = *(const bfrag*)(phi + m*64 + ks*32 + qd*8);
            pf[mt][ks][1] = *(const bfrag*)(plo + m*64 + ks*32 + qd*8);
        }
    }

    ffrag acc[4][4];
    #pragma unroll
    for (int et=0;et<4;++et)
        #pragma unroll
        for (int mt=0;mt<4;++mt){ ffrag z = {0.f,0.f,0.f,0.f}; acc[et][mt] = z; }
    float ks[4] = {0.f,0.f,0.f,0.f};
    float M = -3.0e38f;

    const float* kg = kin + ((size_t)head*NN + n0)*64;

    for (int sub=0; sub<16; ++sub){
        // ---- stage Kn subtile [32 n][64 d], swizzled, + diag via shfl
        {
            int row = t >> 3;
            int g   = t & 7;
            const float* src = kg + (size_t)(sub*32 + row)*64 + g*8;
            float4 x0 = *(const float4*)(src);
            float4 x1 = *(const float4*)(src + 4);
            float xs[8] = {x0.x,x0.y,x0.z,x0.w,x1.x,x1.y,x1.z,x1.w};
            bfrag hv, lv;
            float ss = 0.f;
            #pragma unroll
            for (int j=0;j<8;++j){
                float xn = xs[j]*NORM;
                ss += xn*xn;
                u16 hh,ll; splitf(xn,hh,ll);
                hv[j] = (short)hh; lv[j] = (short)ll;
            }
            int gs = g ^ (row & 7);
            *(bfrag*)(knh + row*64 + gs*8) = hv;
            *(bfrag*)(knl + row*64 + gs*8) = lv;
            ss += __shfl_xor(ss, 1);
            ss += __shfl_xor(ss, 2);
            ss += __shfl_xor(ss, 4);
            if ((t & 7) == 0) diag_s[row] = 0.5f*ss;
        }
        __syncthreads();

        // ---- GEMM1: dash[32 n][256 m] (this wave: its m-quarter)
        ffrag d1[2][4];
        #pragma unroll
        for (int nt=0;nt<2;++nt)
            #pragma unroll
            for (int mt=0;mt<4;++mt){ ffrag z = {0.f,0.f,0.f,0.f}; d1[nt][mt] = z; }
        #pragma unroll
        for (int nt=0;nt<2;++nt){
            int n = nt*16 + li;
            bfrag ah[2], al[2];
            #pragma unroll
            for (int kss=0;kss<2;++kss){
                int gp = (kss*4 + qd) ^ (n & 7);
                ah[kss] = *(const bfrag*)(knh + n*64 + gp*8);
                al[kss] = *(const bfrag*)(knl + n*64 + gp*8);
            }
            #pragma unroll
            for (int mt=0;mt<4;++mt){
                #pragma unroll
                for (int kss=0;kss<2;++kss){
                    d1[nt][mt] = MFMA16(ah[kss], pf[mt][kss][0], d1[nt][mt]);
                    d1[nt][mt] = MFMA16(ah[kss], pf[mt][kss][1], d1[nt][mt]);
                    d1[nt][mt] = MFMA16(al[kss], pf[mt][kss][0], d1[nt][mt]);
                }
            }
        }

        // ---- subtile max (block-wide)
        float mx = -3.0e38f;
        #pragma unroll
        for (int nt=0;nt<2;++nt)
            #pragma unroll
            for (int mt=0;mt<4;++mt)
                #pragma unroll
                for (int rg=0;rg<4;++rg) mx = fmaxf(mx, d1[nt][mt][rg]);
        mx = fmaxf(mx, __shfl_xor(mx, 1));
        mx = fmaxf(mx, __shfl_xor(mx, 2));
        mx = fmaxf(mx, __shfl_xor(mx, 4));
        mx = fmaxf(mx, __shfl_xor(mx, 8));
        mx = fmaxf(mx, __shfl_xor(mx, 16));
        mx = fmaxf(mx, __shfl_xor(mx, 32));
        if (lane == 0) wmax[w] = mx;
        __syncthreads();
        float Ms = fmaxf(fmaxf(wmax[0],wmax[1]), fmaxf(wmax[2],wmax[3]));
        float Mn = fmaxf(M, Ms);
        float r  = __expf(M - Mn);
        M = Mn;
        #pragma unroll
        for (int mt=0;mt<4;++mt) ks[mt] *= r;
        #pragma unroll
        for (int et=0;et<4;++et)
            #pragma unroll
            for (int mt=0;mt<4;++mt)
                #pragma unroll
                for (int rg=0;rg<4;++rg) acc[et][mt][rg] *= r;

        // ---- features -> Bs[m 256][n 32] (transposed, swizzled), + ksum partials
        float sl[4] = {0.f,0.f,0.f,0.f};
        #pragma unroll
        for (int nt=0;nt<2;++nt){
            float d4[4];
            #pragma unroll
            for (int rg=0;rg<4;++rg) d4[rg] = diag_s[nt*16 + qd*4 + rg];
            #pragma unroll
            for (int mt=0;mt<4;++mt){
                int m = w*64 + mt*16 + li;
                u16 h4[4], l4[4];
                #pragma unroll
                for (int rg=0;rg<4;++rg){
                    float f = __expf(d1[nt][mt][rg] - d4[rg] - M);
                    sl[mt] += f;
                    splitf(f, h4[rg], l4[rg]);
                }
                int g  = nt*2 + (qd>>1);
                int gp = g ^ ((m>>1)&3);
                int off = m*32 + gp*8 + (qd&1)*4;
                *(ushort4*)(bsh + off) = make_ushort4(h4[0],h4[1],h4[2],h4[3]);
                *(ushort4*)(bsl + off) = make_ushort4(l4[0],l4[1],l4[2],l4[3]);
            }
        }
        #pragma unroll
        for (int mt=0;mt<4;++mt){
            float v = sl[mt];
            v += __shfl_xor(v, 16);
            v += __shfl_xor(v, 32);
            ks[mt] += v;
        }
        __syncthreads();

        // ---- ctx^T GEMM: acc[e][m] += VT[e][n-chunk] * feat[m][n-chunk]
        bfrag bh[4], bl[4];
        #pragma unroll
        for (int mt=0;mt<4;++mt){
            int m = w*64 + mt*16 + li;
            int gp = qd ^ ((m>>1)&3);
            bh[mt] = *(const bfrag*)(bsh + m*32 + gp*8);
            bl[mt] = *(const bfrag*)(bsl + m*32 + gp*8);
        }
        #pragma unroll
        for (int et=0;et<4;++et){
            int e = et*16 + li;
            size_t vb = ((size_t)head*64 + e)*NN + n0 + sub*32 + qd*8;
            bfrag avh = *(const bfrag*)(vthi + vb);
            bfrag avl = *(const bfrag*)(vtlo + vb);
            #pragma unroll
            for (int mt=0;mt<4;++mt){
                acc[et][mt] = MFMA16(avh, bh[mt], acc[et][mt]);
                acc[et][mt] = MFMA16(avh, bl[mt], acc[et][mt]);
                acc[et][mt] = MFMA16(avl, bh[mt], acc[et][mt]);
            }
        }
        __syncthreads();
    }

    // ---- epilogue: partials [blk][65][256] (row 64 = ksum)
    float* P = ctxPart + (size_t)blk * (65*256);
    #pragma unroll
    for (int et=0;et<4;++et)
        #pragma unroll
        for (int mt=0;mt<4;++mt)
            #pragma unroll
            for (int rg=0;rg<4;++rg){
                int e = et*16 + qd*4 + rg;
                int m = w*64 + mt*16 + li;
                P[e*256 + m] = acc[et][mt][rg];
            }
    if (qd == 0){
        #pragma unroll
        for (int mt=0;mt<4;++mt) P[64*256 + w*64 + mt*16 + li] = ks[mt];
    }
    if (t == 0) mbArr[blk] = M;
}

// ---------------- kred ----------------
__global__ __launch_bounds__(256) void kred(const float* __restrict__ ctxPart,
        const float* __restrict__ mbArr, const float* __restrict__ vsum,
        u16* __restrict__ ctxh, u16* __restrict__ ctxl, float* __restrict__ ksumG){
    int head = blockIdx.x / 65;
    int e = blockIdx.x % 65;
    int m = threadIdx.x;
    float mb[8];
    float mk = -3.0e38f;
    #pragma unroll
    for (int c=0;c<8;++c){ mb[c] = mbArr[head*8+c]; mk = fmaxf(mk, mb[c]); }
    float s = 0.f;
    #pragma unroll
    for (int c=0;c<8;++c){
        float sc = __expf(mb[c] - mk);
        s += sc * ctxPart[((size_t)(head*8+c)*65 + e)*256 + m];
    }
    if (e == 64){
        ksumG[head*256 + m] = s + 4096.0f*EPS;
    } else {
        float val = s + EPS * vsum[head*64 + e];
        u16 h,l; splitf(val,h,l);
        ctxh[((size_t)head*64 + e)*256 + m] = h;
        ctxl[((size_t)head*64 + e)*256 + m] = l;
    }
}

// ---------------- K3: Q-side dash GEMM -> exp -> output GEMM (restructured) ----
// grid 8192; head-XCD swizzle. 64 q-rows per block, 4 waves.
// GEMM1: A=proj (rows=m), B=qn (cols=n) -> d1[mt][nt]: m-contiguous per thread.
// Features stored vectorized to f[n][m] (16B-granule XOR swizzle) = GEMM2 A-layout.
// Denominator computed in registers. GEMM2: waves partition e (ctx read once/block).
__global__ __launch_bounds__(256) __attribute__((amdgpu_waves_per_eu(2,2)))
void k3_kernel(
        const float* __restrict__ qin, const u16* __restrict__ phi, const u16* __restrict__ plo,
        const u16* __restrict__ ctxh, const u16* __restrict__ ctxl,
        const float* __restrict__ ksumG, float* __restrict__ out)
{
    const int bx   = blockIdx.x;
    const int head = (bx & 7) + 8 * ((bx >> 3) & 15);   // heads % 8 colocated per XCD
    const int n0   = (bx >> 7) * 64;
    const int t    = threadIdx.x;
    const int w    = t >> 6;
    const int lane = t & 63;
    const int qd   = lane >> 4;
    const int li   = lane & 15;

    __shared__ __attribute__((aligned(16))) u16 SM[32768];  // 64KB
    u16* qnh = SM;            // [64][64]  (phase 1, aliased)
    u16* qnl = SM + 4096;
    u16* fh  = SM;            // [64][256] (phase 2+)
    u16* fl  = SM + 16384;
    __shared__ float diagq[64], drm[64], dinvs[64], wm[4][64];

    // ---- stage Qn [64][64] hi/lo (swizzled) + diagq
    {
        int row = t >> 2;
        const float* src = qin + ((size_t)head*NN + n0 + row)*64 + (t&3)*16;
        float ss = 0.f;
        #pragma unroll
        for (int gi=0; gi<2; ++gi){
            int g = (t&3)*2 + gi;
            float4 x0 = *(const float4*)(src + gi*8);
            float4 x1 = *(const float4*)(src + gi*8 + 4);
            float xs[8] = {x0.x,x0.y,x0.z,x0.w,x1.x,x1.y,x1.z,x1.w};
            bfrag hv, lv;
            #pragma unroll
            for (int j=0;j<8;++j){
                float xn = xs[j]*NORM;
                ss += xn*xn;
                u16 hh,ll; splitf(xn,hh,ll);
                hv[j] = (short)hh; lv[j] = (short)ll;
            }
            int gs = g ^ (row & 7);
            *(bfrag*)(qnh + row*64 + gs*8) = hv;
            *(bfrag*)(qnl + row*64 + gs*8) = lv;
        }
        ss += __shfl_xor(ss, 1);
        ss += __shfl_xor(ss, 2);
        if ((t&3) == 0) diagq[row] = 0.5f*ss;
    }

    // per-thread ksum values for its 16 m's (m = w*64+mt*16+qd*4+rg)
    float4 ks4[4];
    #pragma unroll
    for (int mt=0;mt<4;++mt)
        ks4[mt] = *(const float4*)(ksumG + head*256 + w*64 + mt*16 + qd*4);
    __syncthreads();

    // ---- GEMM1 (kss-outer; every fragment loaded exactly once)
    ffrag d1[4][4];   // [mt][nt]: m = w*64+mt*16+qd*4+rg, n = nt*16+li
    #pragma unroll
    for (int mt=0;mt<4;++mt)
        #pragma unroll
        for (int nt=0;nt<4;++nt){ ffrag z = {0.f,0.f,0.f,0.f}; d1[mt][nt] = z; }
    #pragma unroll
    for (int kss=0;kss<2;++kss){
        bfrag pfh[4], pfl[4];
        #pragma unroll
        for (int mt=0;mt<4;++mt){
            int m = w*64 + mt*16 + li;
            pfh[mt] = *(const bfrag*)(phi + m*64 + kss*32 + qd*8);
            pfl[mt] = *(const bfrag*)(plo + m*64 + kss*32 + qd*8);
        }
        #pragma unroll
        for (int nt=0;nt<4;++nt){
            int n = nt*16 + li;
            int gp = (kss*4 + qd) ^ (n & 7);
            bfrag bh = *(const bfrag*)(qnh + n*64 + gp*8);
            bfrag bl = *(const bfrag*)(qnl + n*64 + gp*8);
            #pragma unroll
            for (int mt=0;mt<4;++mt){
                d1[mt][nt] = MFMA16(pfh[mt], bh, d1[mt][nt]);
                d1[mt][nt] = MFMA16(pfh[mt], bl, d1[mt][nt]);
                d1[mt][nt] = MFMA16(pfl[mt], bh, d1[mt][nt]);
            }
        }
    }

    // ---- per-n max over m: in-thread (16 vals) + qd-shfl + cross-wave LDS
    #pragma unroll
    for (int nt=0;nt<4;++nt){
        float mx = -3.0e38f;
        #pragma unroll
        for (int mt=0;mt<4;++mt)
            #pragma unroll
            for (int rg=0;rg<4;++rg) mx = fmaxf(mx, d1[mt][nt][rg]);
        mx = fmaxf(mx, __shfl_xor(mx, 16));
        mx = fmaxf(mx, __shfl_xor(mx, 32));
        if (qd == 0) wm[w][nt*16 + li] = mx;
    }
    __syncthreads();
    if (t < 64)
        drm[t] = diagq[t] + fmaxf(fmaxf(wm[0][t], wm[1][t]), fmaxf(wm[2][t], wm[3][t]));
    __syncthreads();

    // ---- features -> f[n][m] vectorized (granule swizzle) + denom partials in regs
    float ds[4] = {0.f,0.f,0.f,0.f};
    #pragma unroll
    for (int nt=0;nt<4;++nt){
        int n = nt*16 + li;
        float dr = drm[n];
        #pragma unroll
        for (int mt=0;mt<4;++mt){
            float fv[4];
            u16 h4[4], l4[4];
            #pragma unroll
            for (int rg=0;rg<4;++rg){
                fv[rg] = __expf(d1[mt][nt][rg] - dr) + EPS;
                splitf(fv[rg], h4[rg], l4[rg]);
            }
            ds[nt] += fv[0]*ks4[mt].x + fv[1]*ks4[mt].y + fv[2]*ks4[mt].z + fv[3]*ks4[mt].w;
            int G  = w*8 + mt*2 + (qd>>1);       // (m0)>>3, m0 = w*64+mt*16+qd*4
            int Gp = G ^ (li & 7);
            int off = n*256 + Gp*8 + (qd&1)*4;   // u16 units
            *(ushort4*)(fh + off) = make_ushort4(h4[0],h4[1],h4[2],h4[3]);
            *(ushort4*)(fl + off) = make_ushort4(l4[0],l4[1],l4[2],l4[3]);
        }
    }
    #pragma unroll
    for (int nt=0;nt<4;++nt){
        float v = ds[nt];
        v += __shfl_xor(v, 16);
        v += __shfl_xor(v, 32);
        if (qd == 0) wm[w][nt*16 + li] = v;
    }
    __syncthreads();
    if (t < 64)
        dinvs[t] = 1.0f / (wm[0][t] + wm[1][t] + wm[2][t] + wm[3][t]);
    __syncthreads();

    // ---- GEMM2: out[n][e] = sum_m f[n][m] * ctx[e][m]; wave = e-quarter
    ffrag a2[4];   // [nt]: n = nt*16+qd*4+rg, e = w*16+li
    #pragma unroll
    for (int nt=0;nt<4;++nt){ ffrag z = {0.f,0.f,0.f,0.f}; a2[nt] = z; }
    const u16* cbh = ctxh + (size_t)head*64*256 + (w*16 + li)*256;
    const u16* cbl = ctxl + (size_t)head*64*256 + (w*16 + li)*256;
    #pragma unroll
    for (int ksm=0; ksm<8; ++ksm){
        bfrag ch = *(const bfrag*)(cbh + ksm*32 + qd*8);
        bfrag cl = *(const bfrag*)(cbl + ksm*32 + qd*8);
        #pragma unroll
        for (int nt=0;nt<4;++nt){
            int n = nt*16 + li;
            int Gp = (ksm*4 + qd) ^ (li & 7);
            bfrag ah2 = *(const bfrag*)(fh + n*256 + Gp*8);
            bfrag al2 = *(const bfrag*)(fl + n*256 + Gp*8);
            a2[nt] = MFMA16(ah2, ch, a2[nt]);
            a2[nt] = MFMA16(ah2, cl, a2[nt]);
            a2[nt] = MFMA16(al2, ch, a2[nt]);
        }
    }

    // ---- epilogue
    float* og = out + ((size_t)head*NN + n0)*64;
    #pragma unroll
    for (int nt=0;nt<4;++nt){
        #pragma unroll
        for (int rg=0;rg<4;++rg){
            int n = nt*16 + qd*4 + rg;
            og[(size_t)n*64 + w*16 + li] = a2[nt][rg] * dinvs[n];
        }
    }
}

extern "C" void kernel_launch(void* const* d_in, const int* in_sizes, int n_in,
                              void* d_out, int out_size, void* d_ws, size_t ws_size,
                              hipStream_t stream) {
    const float* q    = (const float*)d_in[0];
    const float* k    = (const float*)d_in[1];
    const float* v    = (const float*)d_in[2];
    const float* proj = (const float*)d_in[3];
    float* out = (float*)d_out;

    char* wp = (char*)d_ws;
    u16* phi     = (u16*)wp;  wp += (size_t)MM*DD*2;
    u16* plo     = (u16*)wp;  wp += (size_t)MM*DD*2;
    u16* vthi    = (u16*)wp;  wp += (size_t)BH*64*NN*2;
    u16* vtlo    = (u16*)wp;  wp += (size_t)BH*64*NN*2;
    float* vsum  = (float*)wp; wp += (size_t)BH*64*4;
    float* mbArr = (float*)wp; wp += (size_t)1024*4;
    float* ctxPart = (float*)wp; wp += (size_t)1024*65*256*4;
    u16* ctxh    = (u16*)wp;  wp += (size_t)BH*64*256*2;
    u16* ctxl    = (u16*)wp;  wp += (size_t)BH*64*256*2;
    float* ksumG = (float*)wp; wp += (size_t)BH*256*4;

    hipMemsetAsync(vsum, 0, (size_t)BH*64*4, stream);
    p0_proj<<<64, 256, 0, stream>>>(proj, phi, plo);
    p0_vt<<<BH*64, 256, 0, stream>>>(v, vthi, vtlo, vsum);
    kc_kernel<<<1024, 256, 0, stream>>>(k, phi, plo, vthi, vtlo, ctxPart, mbArr);
    kred<<<BH*65, 256, 0, stream>>>(ctxPart, mbArr, vsum, ctxh, ctxl, ksumG);
    k3_kernel<<<BH*64, 256, 0, stream>>>(q, phi, plo, ctxh, ctxl, ksumG, out);
}